// Round 10
// baseline (105.751 us; speedup 1.0000x reference)
//
#include <hip/hip_runtime.h>
#include <hip/hip_bf16.h>
#include <math.h>

#define Bn   16
#define T1n  256
#define T2n  256
#define Dn   256
#define MPn  32

typedef __attribute__((ext_vector_type(8))) short short8;
typedef __attribute__((ext_vector_type(4))) float f32x4;

typedef const __attribute__((address_space(1))) void* gp_t;
typedef __attribute__((address_space(3))) void* lp_t;

__device__ __forceinline__ void gl_lds16(const void* g, void* l) {
  __builtin_amdgcn_global_load_lds((gp_t)g, (lp_t)l, 16, 0, 0);
}
__device__ __forceinline__ void fence() { asm volatile("" ::: "memory"); }
__device__ __forceinline__ void bar() {
  fence();
  __builtin_amdgcn_s_barrier();
  fence();
}
#define WAIT_VM(N) asm volatile("s_waitcnt vmcnt(" #N ")" ::: "memory")

__device__ inline short f2b(float f) {
  __hip_bfloat16 h = __float2bfloat16(f);
  return __builtin_bit_cast(short, h);
}
__device__ inline float b2f(short s) {
  unsigned int u = ((unsigned int)(unsigned short)s) << 16;
  return __builtin_bit_cast(float, u);
}
__device__ inline float max4(f32x4 a) {
  return fmaxf(fmaxf(a.x, a.y), fmaxf(a.z, a.w));
}
__device__ inline int swz_chunk(int row, int d8) {
  return row * 32 + (d8 ^ (row & 7));
}

// ---------------- pre-pass: f32 -> bf16 for lt and rt ----------------
__global__ __launch_bounds__(256, 8)
void cvt_bf16_kernel(const float* __restrict__ lt, const float* __restrict__ rt,
                     short* __restrict__ olt, short* __restrict__ ort) {
  int blk = blockIdx.x;
  const float* src;
  short* dst;
  int t;
  if (blk < 512) { src = lt; dst = olt; t = blk * 256 + threadIdx.x; }
  else           { src = rt; dst = ort; t = (blk - 512) * 256 + threadIdx.x; }
  const f32x4* s = reinterpret_cast<const f32x4*>(src + (size_t)t * 8);
  f32x4 f0 = s[0], f1 = s[1];
  short8 v;
  v[0] = f2b(f0.x); v[1] = f2b(f0.y); v[2] = f2b(f0.z); v[3] = f2b(f0.w);
  v[4] = f2b(f1.x); v[5] = f2b(f1.y); v[6] = f2b(f1.z); v[7] = f2b(f1.w);
  *reinterpret_cast<short8*>(dst + (size_t)t * 8) = v;
}

// ---------------- REAL main (identical to round-6, known ~24us) ----------------
__global__ __launch_bounds__(256, 2)
void mp_match_kernel(const short* __restrict__ ltb,
                     const short* __restrict__ rtb,
                     const float* __restrict__ kern,
                     float* __restrict__ out) {
  __shared__ short lds_rt[64 * 256];
  __shared__ short lds_lt[2][32 * 256];

  const int bid = blockIdx.x;
  const int xcd = bid & 7;
  const int idx = bid >> 3;
  const int b   = ((idx >> 5) << 3) | xcd;
  const int rem = idx & 31;
  const int jblk = rem & 3;
  const int mg   = rem >> 2;
  const int j0   = jblk * 64;

  const int tid  = threadIdx.x;
  const int lane = tid & 63;
  const int w    = tid >> 6;
  const int m    = mg * 4 + w;
  const int bl   = lane & 15;
  const int hl   = lane >> 4;

  const short* lbase = ltb + (size_t)b * T1n * Dn;
  const short* rbase = rtb + ((size_t)b * T2n + j0) * Dn;
  const float* kbase = kern + (size_t)m * Dn;

  int soffL[4];
  #pragma unroll
  for (int it = 0; it < 4; ++it) {
    int cidx = it * 256 + tid;
    int row = cidx >> 5, slot = cidx & 31;
    soffL[it] = row * 256 + (slot ^ (row & 7)) * 8;
  }
  const int wub = (tid & ~63) * 8;

  f32x4 kq[8][2];
  #pragma unroll
  for (int kk = 0; kk < 8; ++kk) {
    const f32x4* kp = reinterpret_cast<const f32x4*>(kbase + (kk * 4 + hl) * 8);
    kq[kk][0] = kp[0];
    kq[kk][1] = kp[1];
  }
  fence();
  #pragma unroll
  for (int it = 0; it < 8; ++it) {
    int cidx = it * 256 + tid;
    int row = cidx >> 5, slot = cidx & 31;
    gl_lds16(rbase + row * 256 + (slot ^ (row & 7)) * 8,
             &lds_rt[it * 256 * 8 + wub]);
  }
  fence();
  #pragma unroll
  for (int it = 0; it < 4; ++it)
    gl_lds16(lbase + soffL[it], &lds_lt[0][it * 256 * 8 + wub]);
  fence();
  #pragma unroll
  for (int it = 0; it < 4; ++it)
    gl_lds16(lbase + 32 * 256 + soffL[it], &lds_lt[1][it * 256 * 8 + wub]);
  fence();

  WAIT_VM(8);
  bar();

  short8 bsc[4][8];
  #pragma unroll
  for (int kk = 0; kk < 8; ++kk) {
    f32x4 k0 = kq[kk][0], k1 = kq[kk][1];
    #pragma unroll
    for (int sub = 0; sub < 4; ++sub) {
      int brow = sub * 16 + bl;
      short8 r = *reinterpret_cast<const short8*>(
          &lds_rt[swz_chunk(brow, kk * 4 + hl) * 8]);
      short8 v;
      v[0] = f2b(b2f(r[0]) * k0.x); v[1] = f2b(b2f(r[1]) * k0.y);
      v[2] = f2b(b2f(r[2]) * k0.z); v[3] = f2b(b2f(r[3]) * k0.w);
      v[4] = f2b(b2f(r[4]) * k1.x); v[5] = f2b(b2f(r[5]) * k1.y);
      v[6] = f2b(b2f(r[6]) * k1.z); v[7] = f2b(b2f(r[7]) * k1.w);
      bsc[sub][kk] = v;
    }
  }

  WAIT_VM(4);
  bar();

  float jmax0 = -1e30f, jmax1 = -1e30f, jmax2 = -1e30f, jmax3 = -1e30f;

  #pragma unroll 1
  for (int ic = 0; ic < 8; ++ic) {
    const int cur = ic & 1;
    const short* lcur = lds_lt[cur];
    __builtin_amdgcn_s_setprio(1);
    #pragma unroll
    for (int it2 = 0; it2 < 2; ++it2) {
      int arow = it2 * 16 + bl;
      f32x4 a0 = {0.f,0.f,0.f,0.f}, a1 = {0.f,0.f,0.f,0.f};
      f32x4 a2 = {0.f,0.f,0.f,0.f}, a3 = {0.f,0.f,0.f,0.f};
      #pragma unroll
      for (int kk = 0; kk < 8; ++kk) {
        short8 A = *reinterpret_cast<const short8*>(
            &lcur[swz_chunk(arow, kk * 4 + hl) * 8]);
        a0 = __builtin_amdgcn_mfma_f32_16x16x32_bf16(A, bsc[0][kk], a0, 0, 0, 0);
        a1 = __builtin_amdgcn_mfma_f32_16x16x32_bf16(A, bsc[1][kk], a1, 0, 0, 0);
        a2 = __builtin_amdgcn_mfma_f32_16x16x32_bf16(A, bsc[2][kk], a2, 0, 0, 0);
        a3 = __builtin_amdgcn_mfma_f32_16x16x32_bf16(A, bsc[3][kk], a3, 0, 0, 0);
      }
      jmax0 = fmaxf(jmax0, max4(a0));
      jmax1 = fmaxf(jmax1, max4(a1));
      jmax2 = fmaxf(jmax2, max4(a2));
      jmax3 = fmaxf(jmax3, max4(a3));
    }
    __builtin_amdgcn_s_setprio(0);
    bar();
    if (ic < 6) {
      #pragma unroll
      for (int it = 0; it < 4; ++it)
        gl_lds16(lbase + (ic + 2) * 32 * 256 + soffL[it],
                 &lds_lt[cur][it * 256 * 8 + wub]);
      fence();
      WAIT_VM(4);
      bar();
    } else if (ic == 6) {
      WAIT_VM(0);
      bar();
    }
  }

  jmax0 = fmaxf(jmax0, __shfl_xor(jmax0, 16));
  jmax0 = fmaxf(jmax0, __shfl_xor(jmax0, 32));
  jmax1 = fmaxf(jmax1, __shfl_xor(jmax1, 16));
  jmax1 = fmaxf(jmax1, __shfl_xor(jmax1, 32));
  jmax2 = fmaxf(jmax2, __shfl_xor(jmax2, 16));
  jmax2 = fmaxf(jmax2, __shfl_xor(jmax2, 32));
  jmax3 = fmaxf(jmax3, __shfl_xor(jmax3, 16));
  jmax3 = fmaxf(jmax3, __shfl_xor(jmax3, 32));
  float v = (hl == 0) ? jmax0 : (hl == 1) ? jmax1 : (hl == 2) ? jmax2 : jmax3;
  int j = j0 + hl * 16 + bl;
  out[((size_t)b * T2n + j) * MPn + m] = tanhf(v);
}

// -------- ABLATION A: staging + sync skeleton only, x12 reps --------
__global__ __launch_bounds__(256, 2)
void stage_only_kernel(const short* __restrict__ ltb,
                       const short* __restrict__ rtb,
                       float* __restrict__ sink) {
  __shared__ short lds_rt[64 * 256];
  __shared__ short lds_lt[2][32 * 256];
  const int bid = blockIdx.x;
  const int xcd = bid & 7;
  const int idx = bid >> 3;
  const int b   = ((idx >> 5) << 3) | xcd;
  const int jblk = (idx & 31) & 3;
  const int j0   = jblk * 64;
  const int tid  = threadIdx.x;

  int soffL[4];
  #pragma unroll
  for (int it = 0; it < 4; ++it) {
    int cidx = it * 256 + tid;
    int row = cidx >> 5, slot = cidx & 31;
    soffL[it] = row * 256 + (slot ^ (row & 7)) * 8;
  }
  const int wub = (tid & ~63) * 8;
  const short* lbase = ltb + (size_t)b * T1n * Dn;
  const short* rbase = rtb + ((size_t)b * T2n + j0) * Dn;

  #pragma unroll 1
  for (int rep = 0; rep < 12; ++rep) {
    #pragma unroll
    for (int it = 0; it < 8; ++it) {
      int cidx = it * 256 + tid;
      int row = cidx >> 5, slot = cidx & 31;
      gl_lds16(rbase + row * 256 + (slot ^ (row & 7)) * 8,
               &lds_rt[it * 256 * 8 + wub]);
    }
    fence();
    #pragma unroll
    for (int it = 0; it < 4; ++it)
      gl_lds16(lbase + soffL[it], &lds_lt[0][it * 256 * 8 + wub]);
    fence();
    #pragma unroll
    for (int it = 0; it < 4; ++it)
      gl_lds16(lbase + 32 * 256 + soffL[it], &lds_lt[1][it * 256 * 8 + wub]);
    fence();
    WAIT_VM(8);
    bar();
    WAIT_VM(4);
    bar();
    #pragma unroll 1
    for (int ic = 0; ic < 8; ++ic) {
      bar();
      if (ic < 6) {
        #pragma unroll
        for (int it = 0; it < 4; ++it)
          gl_lds16(lbase + (ic + 2) * 32 * 256 + soffL[it],
                   &lds_lt[ic & 1][it * 256 * 8 + wub]);
        fence();
        WAIT_VM(4);
        bar();
      } else if (ic == 6) {
        WAIT_VM(0);
        bar();
      }
    }
  }
  if (tid == 0) sink[bid] = (float)lds_rt[0];
}

// -------- ABLATION B: stage once, then compute loop only, x4 reps --------
__global__ __launch_bounds__(256, 2)
void compute_only_kernel(const short* __restrict__ ltb,
                         const short* __restrict__ rtb,
                         const float* __restrict__ kern,
                         float* __restrict__ sink) {
  __shared__ short lds_rt[64 * 256];
  __shared__ short lds_lt[2][32 * 256];
  const int bid = blockIdx.x;
  const int xcd = bid & 7;
  const int idx = bid >> 3;
  const int b   = ((idx >> 5) << 3) | xcd;
  const int rem = idx & 31;
  const int jblk = rem & 3;
  const int mg   = rem >> 2;
  const int j0   = jblk * 64;
  const int tid  = threadIdx.x;
  const int lane = tid & 63;
  const int w    = tid >> 6;
  const int m    = mg * 4 + w;
  const int bl   = lane & 15;
  const int hl   = lane >> 4;

  const short* lbase = ltb + (size_t)b * T1n * Dn;
  const short* rbase = rtb + ((size_t)b * T2n + j0) * Dn;
  const float* kbase = kern + (size_t)m * Dn;

  int soffL[4];
  #pragma unroll
  for (int it = 0; it < 4; ++it) {
    int cidx = it * 256 + tid;
    int row = cidx >> 5, slot = cidx & 31;
    soffL[it] = row * 256 + (slot ^ (row & 7)) * 8;
  }
  const int wub = (tid & ~63) * 8;

  // stage rt + lt c0 + c1 ONCE
  #pragma unroll
  for (int it = 0; it < 8; ++it) {
    int cidx = it * 256 + tid;
    int row = cidx >> 5, slot = cidx & 31;
    gl_lds16(rbase + row * 256 + (slot ^ (row & 7)) * 8,
             &lds_rt[it * 256 * 8 + wub]);
  }
  fence();
  #pragma unroll
  for (int it = 0; it < 4; ++it)
    gl_lds16(lbase + soffL[it], &lds_lt[0][it * 256 * 8 + wub]);
  fence();
  #pragma unroll
  for (int it = 0; it < 4; ++it)
    gl_lds16(lbase + 32 * 256 + soffL[it], &lds_lt[1][it * 256 * 8 + wub]);
  fence();
  WAIT_VM(0);
  bar();

  short8 bsc[4][8];
  #pragma unroll
  for (int kk = 0; kk < 8; ++kk) {
    const f32x4* kp = reinterpret_cast<const f32x4*>(kbase + (kk * 4 + hl) * 8);
    f32x4 k0 = kp[0], k1 = kp[1];
    #pragma unroll
    for (int sub = 0; sub < 4; ++sub) {
      int brow = sub * 16 + bl;
      short8 r = *reinterpret_cast<const short8*>(
          &lds_rt[swz_chunk(brow, kk * 4 + hl) * 8]);
      short8 v;
      v[0] = f2b(b2f(r[0]) * k0.x); v[1] = f2b(b2f(r[1]) * k0.y);
      v[2] = f2b(b2f(r[2]) * k0.z); v[3] = f2b(b2f(r[3]) * k0.w);
      v[4] = f2b(b2f(r[4]) * k1.x); v[5] = f2b(b2f(r[5]) * k1.y);
      v[6] = f2b(b2f(r[6]) * k1.z); v[7] = f2b(b2f(r[7]) * k1.w);
      bsc[sub][kk] = v;
    }
  }
  bar();

  float jmax0 = -1e30f, jmax1 = -1e30f, jmax2 = -1e30f, jmax3 = -1e30f;

  #pragma unroll 1
  for (int rep = 0; rep < 4; ++rep) {
    #pragma unroll 1
    for (int ic = 0; ic < 8; ++ic) {
      const short* lcur = lds_lt[ic & 1];
      __builtin_amdgcn_s_setprio(1);
      #pragma unroll
      for (int it2 = 0; it2 < 2; ++it2) {
        int arow = it2 * 16 + bl;
        f32x4 a0 = {0.f,0.f,0.f,0.f}, a1 = {0.f,0.f,0.f,0.f};
        f32x4 a2 = {0.f,0.f,0.f,0.f}, a3 = {0.f,0.f,0.f,0.f};
        #pragma unroll
        for (int kk = 0; kk < 8; ++kk) {
          short8 A = *reinterpret_cast<const short8*>(
              &lcur[swz_chunk(arow, kk * 4 + hl) * 8]);
          a0 = __builtin_amdgcn_mfma_f32_16x16x32_bf16(A, bsc[0][kk], a0, 0, 0, 0);
          a1 = __builtin_amdgcn_mfma_f32_16x16x32_bf16(A, bsc[1][kk], a1, 0, 0, 0);
          a2 = __builtin_amdgcn_mfma_f32_16x16x32_bf16(A, bsc[2][kk], a2, 0, 0, 0);
          a3 = __builtin_amdgcn_mfma_f32_16x16x32_bf16(A, bsc[3][kk], a3, 0, 0, 0);
        }
        jmax0 = fmaxf(jmax0, max4(a0));
        jmax1 = fmaxf(jmax1, max4(a1));
        jmax2 = fmaxf(jmax2, max4(a2));
        jmax3 = fmaxf(jmax3, max4(a3));
      }
      __builtin_amdgcn_s_setprio(0);
      bar();
      bar();
    }
  }

  float v = (hl == 0) ? jmax0 : (hl == 1) ? jmax1 : (hl == 2) ? jmax2 : jmax3;
  sink[(size_t)bid * 256 + tid] = v;
}

extern "C" void kernel_launch(void* const* d_in, const int* in_sizes, int n_in,
                              void* d_out, int out_size, void* d_ws, size_t ws_size,
                              hipStream_t stream) {
  const float* lt   = (const float*)d_in[0];
  const float* rt   = (const float*)d_in[1];
  const float* kern = (const float*)d_in[2];
  float* out = (float*)d_out;

  short* ltb = (short*)d_ws;
  short* rtb = ltb + (size_t)Bn * T1n * Dn;
  float* sink1 = (float*)((char*)d_ws + (16u << 20));
  float* sink2 = (float*)((char*)d_ws + (24u << 20));

  cvt_bf16_kernel<<<1024, 256, 0, stream>>>(lt, rt, ltb, rtb);
  mp_match_kernel<<<512, 256, 0, stream>>>(ltb, rtb, kern, out);
  stage_only_kernel<<<512, 256, 0, stream>>>(ltb, rtb, sink1);
  compute_only_kernel<<<512, 256, 0, stream>>>(ltb, rtb, kern, sink2);
}